// Round 6
// baseline (627.928 us; speedup 1.0000x reference)
//
#include <hip/hip_runtime.h>
#include <math.h>

#define N_NODES 100000
#define N_EDGES 1600000
#define DIM_IN  256
#define DIM_H   64
#define DIM_C   47
#define DIM_CP  48                            // padded h2 row stride (192B aligned)
#define SCAN_CHUNK 1024                       // elems per scan block (256 thr x 4)
#define NBLK_SCAN ((N_NODES + SCAN_CHUNK - 1) / SCAN_CHUNK)   // 98

// ---------- zero int buffers (cnt, cursor) ----------
__global__ __launch_bounds__(256) void k_zero(int* __restrict__ cnt,
                                              int* __restrict__ cursor) {
  int i = blockIdx.x * 256 + threadIdx.x;
  if (i < N_NODES) { cnt[i] = 0; cursor[i] = 0; }
}

// ---------- in-degree histogram ----------
__global__ __launch_bounds__(256) void k_hist(const int* __restrict__ dst,
                                              int* __restrict__ cnt) {
  int e = blockIdx.x * 256 + threadIdx.x;
  if (e < N_EDGES) atomicAdd(&cnt[dst[e]], 1);
}

// ---------- dinv = rsqrt(deg+1)  (self-loop) ----------
__global__ __launch_bounds__(256) void k_dinv(const int* __restrict__ cnt,
                                              float* __restrict__ dinv) {
  int i = blockIdx.x * 256 + threadIdx.x;
  if (i < N_NODES) dinv[i] = rsqrtf((float)cnt[i] + 1.0f);
}

// ---------- pad W2 (64x47) into W2p (64x48, zero pad col) ----------
__global__ __launch_bounds__(256) void k_padW2(const float* __restrict__ W2,
                                               float* __restrict__ W2p) {
  int i = blockIdx.x * 256 + threadIdx.x;
  if (i >= DIM_H * DIM_CP) return;
  int k = i / DIM_CP, j = i % DIM_CP;
  W2p[i] = (j < DIM_C) ? W2[k * DIM_C + j] : 0.f;
}

// ---------- exclusive scan of cnt -> row_start (3 kernels) ----------
__global__ __launch_bounds__(256) void k_scan_partial(const int* __restrict__ cnt,
                                                      int* __restrict__ row_start,
                                                      int* __restrict__ blk_sums) {
  __shared__ int ls[256];
  const int tid  = threadIdx.x;
  const int base = blockIdx.x * SCAN_CHUNK + tid * 4;
  int c0 = (base + 0 < N_NODES) ? cnt[base + 0] : 0;
  int c1 = (base + 1 < N_NODES) ? cnt[base + 1] : 0;
  int c2 = (base + 2 < N_NODES) ? cnt[base + 2] : 0;
  int c3 = (base + 3 < N_NODES) ? cnt[base + 3] : 0;
  int tsum = c0 + c1 + c2 + c3;
  ls[tid] = tsum;
  __syncthreads();
  for (int off = 1; off < 256; off <<= 1) {
    int v = (tid >= off) ? ls[tid - off] : 0;
    __syncthreads();
    ls[tid] += v;
    __syncthreads();
  }
  int excl = ls[tid] - tsum;
  if (base + 0 < N_NODES) row_start[base + 0] = excl;
  if (base + 1 < N_NODES) row_start[base + 1] = excl + c0;
  if (base + 2 < N_NODES) row_start[base + 2] = excl + c0 + c1;
  if (base + 3 < N_NODES) row_start[base + 3] = excl + c0 + c1 + c2;
  if (tid == 255) blk_sums[blockIdx.x] = ls[255];
}

__global__ __launch_bounds__(128) void k_scan_blk(int* __restrict__ blk_sums) {
  __shared__ int ls[128];
  const int tid = threadIdx.x;
  int v = (tid < NBLK_SCAN) ? blk_sums[tid] : 0;
  ls[tid] = v;
  __syncthreads();
  for (int off = 1; off < 128; off <<= 1) {
    int u = (tid >= off) ? ls[tid - off] : 0;
    __syncthreads();
    ls[tid] += u;
    __syncthreads();
  }
  if (tid < NBLK_SCAN) blk_sums[tid] = ls[tid] - v;
}

__global__ __launch_bounds__(256) void k_scan_add(int* __restrict__ row_start,
                                                  const int* __restrict__ blk_sums) {
  int i = blockIdx.x * 256 + threadIdx.x;
  if (i < N_NODES) row_start[i] += blk_sums[i / SCAN_CHUNK];
}

// ---------- scatter src ids into dst-sorted order ----------
__global__ __launch_bounds__(256) void k_scatter(const int* __restrict__ src,
                                                 const int* __restrict__ dst,
                                                 const int* __restrict__ row_start,
                                                 int* __restrict__ cursor,
                                                 int* __restrict__ sorted_src) {
  int e = blockIdx.x * 256 + threadIdx.x;
  if (e >= N_EDGES) return;
  int d = dst[e];
  int pos = row_start[d] + atomicAdd(&cursor[d], 1);
  sorted_src[pos] = src[e];
}

// ---------- layer 1 GEMM + dinv pre-scale: h1s = dinv[n] * (x @ W1) ----------
// Block = 4 waves x 64 lanes = one 64-row tile. Wave w -> cols [16w,16w+16);
// lane -> row. W reads wave-uniform (SGPR), 16 acc VGPRs, no LDS.
__global__ __launch_bounds__(256) void k_gemm1(const float* __restrict__ x,
                                               const float* __restrict__ W,
                                               const float* __restrict__ dinv,
                                               float* __restrict__ h1s) {
  const int lane = threadIdx.x & 63;
  const int j0   = (threadIdx.x >> 6) * 16;   // wave-uniform col base
  int row = blockIdx.x * 64 + lane;
  if (row >= N_NODES) row = N_NODES - 1;  // clamp: duplicate work, identical values
  const float4* xr = (const float4*)(x + (size_t)row * DIM_IN);

  float acc[16];
#pragma unroll
  for (int j = 0; j < 16; ++j) acc[j] = 0.f;

#pragma unroll 1
  for (int k4 = 0; k4 < DIM_IN / 4; ++k4) {
    float4 xv = xr[k4];
#pragma unroll
    for (int kk = 0; kk < 4; ++kk) {
      float xk = (kk == 0) ? xv.x : (kk == 1) ? xv.y : (kk == 2) ? xv.z : xv.w;
      const float* wrow = W + (size_t)(4 * k4 + kk) * DIM_H + j0;  // wave-uniform
#pragma unroll
      for (int j = 0; j < 16; ++j)
        acc[j] = fmaf(xk, wrow[j], acc[j]);
    }
  }

  float di = dinv[row];
  float4* out = (float4*)(h1s + (size_t)row * DIM_H + j0);
#pragma unroll
  for (int j4 = 0; j4 < 4; ++j4)
    out[j4] = make_float4(di * acc[4 * j4], di * acc[4 * j4 + 1],
                          di * acc[4 * j4 + 2], di * acc[4 * j4 + 3]);
}

// ---------- agg1 gather: wave per node, lane = channel, 4-way unrolled CSR loop ----------
__global__ __launch_bounds__(256) void k_agg1_gather(const float* __restrict__ h1s,
                                                     const float* __restrict__ dinv,
                                                     const float* __restrict__ b1,
                                                     const int* __restrict__ row_start,
                                                     const int* __restrict__ cnt,
                                                     const int* __restrict__ sorted_src,
                                                     float* __restrict__ agg1) {
  int n = blockIdx.x * 4 + (threadIdx.x >> 6);
  int j = threadIdx.x & 63;
  if (n >= N_NODES) return;
  int start = row_start[n];
  int deg   = cnt[n];
  float acc0 = h1s[(size_t)n * DIM_H + j];  // self term
  float acc1 = 0.f, acc2 = 0.f, acc3 = 0.f;
  int k = 0;
  for (; k + 4 <= deg; k += 4) {
    int s0 = sorted_src[start + k + 0];
    int s1 = sorted_src[start + k + 1];
    int s2 = sorted_src[start + k + 2];
    int s3 = sorted_src[start + k + 3];
    acc0 += h1s[(size_t)s0 * DIM_H + j];
    acc1 += h1s[(size_t)s1 * DIM_H + j];
    acc2 += h1s[(size_t)s2 * DIM_H + j];
    acc3 += h1s[(size_t)s3 * DIM_H + j];
  }
  for (; k < deg; ++k)
    acc0 += h1s[(size_t)sorted_src[start + k] * DIM_H + j];
  float di = dinv[n];
  agg1[(size_t)n * DIM_H + j] = di * ((acc0 + acc1) + (acc2 + acc3)) + b1[j];
}

// ---------- layer 2 GEMM + ReLU + dinv pre-scale: h2p = dinv[n]*(relu(agg1) @ W2p) ----------
// Block = 3 waves x 64 lanes. Wave w -> cols [16w,16w+16) of padded 48; lane -> row.
__global__ __launch_bounds__(192) void k_gemm2(const float* __restrict__ agg1,
                                               const float* __restrict__ W2p,
                                               const float* __restrict__ dinv,
                                               float* __restrict__ h2p) {
  const int lane = threadIdx.x & 63;
  const int j0   = (threadIdx.x >> 6) * 16;   // 0,16,32 (wave-uniform)
  int row = blockIdx.x * 64 + lane;
  if (row >= N_NODES) row = N_NODES - 1;
  const float4* xr = (const float4*)(agg1 + (size_t)row * DIM_H);

  float acc[16];
#pragma unroll
  for (int j = 0; j < 16; ++j) acc[j] = 0.f;

#pragma unroll 1
  for (int k4 = 0; k4 < DIM_H / 4; ++k4) {
    float4 xv = xr[k4];
    xv.x = fmaxf(xv.x, 0.f); xv.y = fmaxf(xv.y, 0.f);
    xv.z = fmaxf(xv.z, 0.f); xv.w = fmaxf(xv.w, 0.f);
#pragma unroll
    for (int kk = 0; kk < 4; ++kk) {
      float xk = (kk == 0) ? xv.x : (kk == 1) ? xv.y : (kk == 2) ? xv.z : xv.w;
      const float* wrow = W2p + (size_t)(4 * k4 + kk) * DIM_CP + j0;  // wave-uniform
#pragma unroll
      for (int j = 0; j < 16; ++j)
        acc[j] = fmaf(xk, wrow[j], acc[j]);
    }
  }

  float di = dinv[row];
  float4* out = (float4*)(h2p + (size_t)row * DIM_CP + j0);
#pragma unroll
  for (int j4 = 0; j4 < 4; ++j4)
    out[j4] = make_float4(di * acc[4 * j4], di * acc[4 * j4 + 1],
                          di * acc[4 * j4 + 2], di * acc[4 * j4 + 3]);
  // pad col 47 gets di*acc[15] where acc[15] accumulated W2p[..][47]=0 -> stays 0. OK.
}

// ---------- agg2 gather + fused log_softmax: wave per node, 4-way unrolled ----------
__global__ __launch_bounds__(256) void k_agg2_gather(const float* __restrict__ h2p,
                                                     const float* __restrict__ dinv,
                                                     const float* __restrict__ b2,
                                                     const int* __restrict__ row_start,
                                                     const int* __restrict__ cnt,
                                                     const int* __restrict__ sorted_src,
                                                     float* __restrict__ out) {
  int n = blockIdx.x * 4 + (threadIdx.x >> 6);
  int j = threadIdx.x & 63;
  if (n >= N_NODES) return;
  int jj = (j < DIM_C) ? j : DIM_C;  // lanes >=47 read the zero pad
  int start = row_start[n];
  int deg   = cnt[n];
  float acc0 = h2p[(size_t)n * DIM_CP + jj];  // self term
  float acc1 = 0.f, acc2 = 0.f, acc3 = 0.f;
  int k = 0;
  for (; k + 4 <= deg; k += 4) {
    int s0 = sorted_src[start + k + 0];
    int s1 = sorted_src[start + k + 1];
    int s2 = sorted_src[start + k + 2];
    int s3 = sorted_src[start + k + 3];
    acc0 += h2p[(size_t)s0 * DIM_CP + jj];
    acc1 += h2p[(size_t)s1 * DIM_CP + jj];
    acc2 += h2p[(size_t)s2 * DIM_CP + jj];
    acc3 += h2p[(size_t)s3 * DIM_CP + jj];
  }
  for (; k < deg; ++k)
    acc0 += h2p[(size_t)sorted_src[start + k] * DIM_CP + jj];
  float di = dinv[n];
  float acc = di * ((acc0 + acc1) + (acc2 + acc3)) + ((j < DIM_C) ? b2[jj] : 0.f);

  // fused log_softmax over the 47 classes
  float v = (j < DIM_C) ? acc : -INFINITY;
  float m = v;
  for (int o = 32; o; o >>= 1) m = fmaxf(m, __shfl_xor(m, o));
  float ex = (j < DIM_C) ? __expf(v - m) : 0.0f;
  float s = ex;
  for (int o = 32; o; o >>= 1) s += __shfl_xor(s, o);
  if (j < DIM_C) out[(size_t)n * DIM_C + j] = v - m - __logf(s);
}

extern "C" void kernel_launch(void* const* d_in, const int* in_sizes, int n_in,
                              void* d_out, int out_size, void* d_ws, size_t ws_size,
                              hipStream_t stream) {
  const float* x  = (const float*)d_in[0];
  const float* W1 = (const float*)d_in[1];
  const float* b1 = (const float*)d_in[2];
  const float* W2 = (const float*)d_in[3];
  const float* b2 = (const float*)d_in[4];
  const int*   ei = (const int*)d_in[5];
  const int* src = ei;
  const int* dst = ei + N_EDGES;
  float* out = (float*)d_out;

  float* ws   = (float*)d_ws;
  float* dinv = ws;                                   // N
  float* W2p  = dinv + N_NODES;                       // 64*48
  float* h1s  = W2p + DIM_H * DIM_CP;                 // N*64 (reused for h2p, N*48)
  float* agg1 = h1s + (size_t)N_NODES * DIM_H;        // N*64
  float* h2p  = h1s;                                  // alias: h1s dead after agg1_gather
  int* ibuf       = (int*)(agg1 + (size_t)N_NODES * DIM_H);
  int* cnt        = ibuf;                             // N
  int* cursor     = cnt + N_NODES;                    // N
  int* row_start  = cursor + N_NODES;                 // N
  int* blk_sums   = row_start + N_NODES;              // 128
  int* sorted_src = blk_sums + 128;                   // E

  const int nblk_n  = (N_NODES + 255) / 256;
  const int nblk_e  = (N_EDGES + 255) / 256;
  const int nblk_nw = (N_NODES + 3) / 4;              // wave-per-node gathers
  const int nblk_g  = (N_NODES + 63) / 64;            // 64-row GEMM tiles

  // CSR build + weight pad
  k_zero<<<nblk_n, 256, 0, stream>>>(cnt, cursor);
  k_hist<<<nblk_e, 256, 0, stream>>>(dst, cnt);
  k_dinv<<<nblk_n, 256, 0, stream>>>(cnt, dinv);
  k_padW2<<<(DIM_H * DIM_CP + 255) / 256, 256, 0, stream>>>(W2, W2p);
  k_scan_partial<<<NBLK_SCAN, 256, 0, stream>>>(cnt, row_start, blk_sums);
  k_scan_blk<<<1, 128, 0, stream>>>(blk_sums);
  k_scan_add<<<nblk_n, 256, 0, stream>>>(row_start, blk_sums);
  k_scatter<<<nblk_e, 256, 0, stream>>>(src, dst, row_start, cursor, sorted_src);

  // layer 1
  k_gemm1<<<nblk_g, 256, 0, stream>>>(x, W1, dinv, h1s);
  k_agg1_gather<<<nblk_nw, 256, 0, stream>>>(h1s, dinv, b1, row_start, cnt, sorted_src, agg1);

  // layer 2 (+ fused log_softmax)
  k_gemm2<<<nblk_g, 192, 0, stream>>>(agg1, W2p, dinv, h2p);
  k_agg2_gather<<<nblk_nw, 256, 0, stream>>>(h2p, dinv, b2, row_start, cnt, sorted_src, out);
}

// Round 7
// 417.081 us; speedup vs baseline: 1.5055x; 1.5055x over previous
//
#include <hip/hip_runtime.h>
#include <math.h>

#define N_NODES 100000
#define N_EDGES 1600000
#define DIM_IN  256
#define DIM_H   64
#define DIM_C   47
#define DIM_CP  48                            // padded h2 row stride (192B aligned)
#define SCAN_CHUNK 1024                       // elems per scan block (256 thr x 4)
#define NBLK_SCAN ((N_NODES + SCAN_CHUNK - 1) / SCAN_CHUNK)   // 98

// ---------- zero int buffers (cnt, cursor) ----------
__global__ __launch_bounds__(256) void k_zero(int* __restrict__ cnt,
                                              int* __restrict__ cursor) {
  int i = blockIdx.x * 256 + threadIdx.x;
  if (i < N_NODES) { cnt[i] = 0; cursor[i] = 0; }
}

// ---------- in-degree histogram ----------
__global__ __launch_bounds__(256) void k_hist(const int* __restrict__ dst,
                                              int* __restrict__ cnt) {
  int e = blockIdx.x * 256 + threadIdx.x;
  if (e < N_EDGES) atomicAdd(&cnt[dst[e]], 1);
}

// ---------- dinv = rsqrt(deg+1)  (self-loop) ----------
__global__ __launch_bounds__(256) void k_dinv(const int* __restrict__ cnt,
                                              float* __restrict__ dinv) {
  int i = blockIdx.x * 256 + threadIdx.x;
  if (i < N_NODES) dinv[i] = rsqrtf((float)cnt[i] + 1.0f);
}

// ---------- pad W2 (64x47) into W2p (64x48, zero pad col) ----------
__global__ __launch_bounds__(256) void k_padW2(const float* __restrict__ W2,
                                               float* __restrict__ W2p) {
  int i = blockIdx.x * 256 + threadIdx.x;
  if (i >= DIM_H * DIM_CP) return;
  int k = i / DIM_CP, j = i % DIM_CP;
  W2p[i] = (j < DIM_C) ? W2[k * DIM_C + j] : 0.f;
}

// ---------- exclusive scan of cnt -> row_start (3 kernels) ----------
__global__ __launch_bounds__(256) void k_scan_partial(const int* __restrict__ cnt,
                                                      int* __restrict__ row_start,
                                                      int* __restrict__ blk_sums) {
  __shared__ int ls[256];
  const int tid  = threadIdx.x;
  const int base = blockIdx.x * SCAN_CHUNK + tid * 4;
  int c0 = (base + 0 < N_NODES) ? cnt[base + 0] : 0;
  int c1 = (base + 1 < N_NODES) ? cnt[base + 1] : 0;
  int c2 = (base + 2 < N_NODES) ? cnt[base + 2] : 0;
  int c3 = (base + 3 < N_NODES) ? cnt[base + 3] : 0;
  int tsum = c0 + c1 + c2 + c3;
  ls[tid] = tsum;
  __syncthreads();
  for (int off = 1; off < 256; off <<= 1) {
    int v = (tid >= off) ? ls[tid - off] : 0;
    __syncthreads();
    ls[tid] += v;
    __syncthreads();
  }
  int excl = ls[tid] - tsum;
  if (base + 0 < N_NODES) row_start[base + 0] = excl;
  if (base + 1 < N_NODES) row_start[base + 1] = excl + c0;
  if (base + 2 < N_NODES) row_start[base + 2] = excl + c0 + c1;
  if (base + 3 < N_NODES) row_start[base + 3] = excl + c0 + c1 + c2;
  if (tid == 255) blk_sums[blockIdx.x] = ls[255];
}

__global__ __launch_bounds__(128) void k_scan_blk(int* __restrict__ blk_sums) {
  __shared__ int ls[128];
  const int tid = threadIdx.x;
  int v = (tid < NBLK_SCAN) ? blk_sums[tid] : 0;
  ls[tid] = v;
  __syncthreads();
  for (int off = 1; off < 128; off <<= 1) {
    int u = (tid >= off) ? ls[tid - off] : 0;
    __syncthreads();
    ls[tid] += u;
    __syncthreads();
  }
  if (tid < NBLK_SCAN) blk_sums[tid] = ls[tid] - v;
}

__global__ __launch_bounds__(256) void k_scan_add(int* __restrict__ row_start,
                                                  const int* __restrict__ blk_sums) {
  int i = blockIdx.x * 256 + threadIdx.x;
  if (i < N_NODES) row_start[i] += blk_sums[i / SCAN_CHUNK];
}

// ---------- scatter src ids into dst-sorted order ----------
__global__ __launch_bounds__(256) void k_scatter(const int* __restrict__ src,
                                                 const int* __restrict__ dst,
                                                 const int* __restrict__ row_start,
                                                 int* __restrict__ cursor,
                                                 int* __restrict__ sorted_src) {
  int e = blockIdx.x * 256 + threadIdx.x;
  if (e >= N_EDGES) return;
  int d = dst[e];
  int pos = row_start[d] + atomicAdd(&cursor[d], 1);
  sorted_src[pos] = src[e];
}

// ---------- layer 1 GEMM + dinv pre-scale: h1s = dinv[n] * (x @ W1) ----------
// Block = 4 waves x 64 lanes = one 64-row tile. Wave w -> cols [16w,16w+16);
// lane -> row. j0 forced into SGPR via readfirstlane so W reads stay s_load
// (LLVM treats threadIdx-derived values as divergent otherwise -> R5 regression).
__global__ __launch_bounds__(256) void k_gemm1(const float* __restrict__ x,
                                               const float* __restrict__ W,
                                               const float* __restrict__ dinv,
                                               float* __restrict__ h1s) {
  const int lane = threadIdx.x & 63;
  const int j0   = __builtin_amdgcn_readfirstlane((threadIdx.x >> 6) * 16);
  int row = blockIdx.x * 64 + lane;
  if (row >= N_NODES) row = N_NODES - 1;  // clamp: duplicate work, identical values
  const float4* xr = (const float4*)(x + (size_t)row * DIM_IN);

  float acc[16];
#pragma unroll
  for (int j = 0; j < 16; ++j) acc[j] = 0.f;

#pragma unroll 1
  for (int k4 = 0; k4 < DIM_IN / 4; ++k4) {
    float4 xv = xr[k4];
#pragma unroll
    for (int kk = 0; kk < 4; ++kk) {
      float xk = (kk == 0) ? xv.x : (kk == 1) ? xv.y : (kk == 2) ? xv.z : xv.w;
      const float* wrow = W + (size_t)(4 * k4 + kk) * DIM_H + j0;  // uniform -> s_load
#pragma unroll
      for (int j = 0; j < 16; ++j)
        acc[j] = fmaf(xk, wrow[j], acc[j]);
    }
  }

  float di = dinv[row];
  float4* out = (float4*)(h1s + (size_t)row * DIM_H + j0);
#pragma unroll
  for (int j4 = 0; j4 < 4; ++j4)
    out[j4] = make_float4(di * acc[4 * j4], di * acc[4 * j4 + 1],
                          di * acc[4 * j4 + 2], di * acc[4 * j4 + 3]);
}

// ---------- agg1 gather: wave per node, lane = channel, 4-way unrolled CSR loop ----------
__global__ __launch_bounds__(256) void k_agg1_gather(const float* __restrict__ h1s,
                                                     const float* __restrict__ dinv,
                                                     const float* __restrict__ b1,
                                                     const int* __restrict__ row_start,
                                                     const int* __restrict__ cnt,
                                                     const int* __restrict__ sorted_src,
                                                     float* __restrict__ agg1) {
  int n = blockIdx.x * 4 + (threadIdx.x >> 6);
  int j = threadIdx.x & 63;
  if (n >= N_NODES) return;
  int start = row_start[n];
  int deg   = cnt[n];
  float acc0 = h1s[(size_t)n * DIM_H + j];  // self term
  float acc1 = 0.f, acc2 = 0.f, acc3 = 0.f;
  int k = 0;
  for (; k + 4 <= deg; k += 4) {
    int s0 = sorted_src[start + k + 0];
    int s1 = sorted_src[start + k + 1];
    int s2 = sorted_src[start + k + 2];
    int s3 = sorted_src[start + k + 3];
    acc0 += h1s[(size_t)s0 * DIM_H + j];
    acc1 += h1s[(size_t)s1 * DIM_H + j];
    acc2 += h1s[(size_t)s2 * DIM_H + j];
    acc3 += h1s[(size_t)s3 * DIM_H + j];
  }
  for (; k < deg; ++k)
    acc0 += h1s[(size_t)sorted_src[start + k] * DIM_H + j];
  float di = dinv[n];
  agg1[(size_t)n * DIM_H + j] = di * ((acc0 + acc1) + (acc2 + acc3)) + b1[j];
}

// ---------- layer 2 GEMM + ReLU + dinv pre-scale: h2p = dinv[n]*(relu(agg1) @ W2p) ----------
// Block = 3 waves x 64 lanes. Wave w -> cols [16w,16w+16) of padded 48; lane -> row.
__global__ __launch_bounds__(192) void k_gemm2(const float* __restrict__ agg1,
                                               const float* __restrict__ W2p,
                                               const float* __restrict__ dinv,
                                               float* __restrict__ h2p) {
  const int lane = threadIdx.x & 63;
  const int j0   = __builtin_amdgcn_readfirstlane((threadIdx.x >> 6) * 16);
  int row = blockIdx.x * 64 + lane;
  if (row >= N_NODES) row = N_NODES - 1;
  const float4* xr = (const float4*)(agg1 + (size_t)row * DIM_H);

  float acc[16];
#pragma unroll
  for (int j = 0; j < 16; ++j) acc[j] = 0.f;

#pragma unroll 1
  for (int k4 = 0; k4 < DIM_H / 4; ++k4) {
    float4 xv = xr[k4];
    xv.x = fmaxf(xv.x, 0.f); xv.y = fmaxf(xv.y, 0.f);
    xv.z = fmaxf(xv.z, 0.f); xv.w = fmaxf(xv.w, 0.f);
#pragma unroll
    for (int kk = 0; kk < 4; ++kk) {
      float xk = (kk == 0) ? xv.x : (kk == 1) ? xv.y : (kk == 2) ? xv.z : xv.w;
      const float* wrow = W2p + (size_t)(4 * k4 + kk) * DIM_CP + j0;  // uniform -> s_load
#pragma unroll
      for (int j = 0; j < 16; ++j)
        acc[j] = fmaf(xk, wrow[j], acc[j]);
    }
  }

  float di = dinv[row];
  float4* out = (float4*)(h2p + (size_t)row * DIM_CP + j0);
#pragma unroll
  for (int j4 = 0; j4 < 4; ++j4)
    out[j4] = make_float4(di * acc[4 * j4], di * acc[4 * j4 + 1],
                          di * acc[4 * j4 + 2], di * acc[4 * j4 + 3]);
  // pad col 47 gets di*acc[15] where acc[15] accumulated W2p[..][47]=0 -> stays 0. OK.
}

// ---------- agg2 gather + fused log_softmax: wave per node, 4-way unrolled ----------
__global__ __launch_bounds__(256) void k_agg2_gather(const float* __restrict__ h2p,
                                                     const float* __restrict__ dinv,
                                                     const float* __restrict__ b2,
                                                     const int* __restrict__ row_start,
                                                     const int* __restrict__ cnt,
                                                     const int* __restrict__ sorted_src,
                                                     float* __restrict__ out) {
  int n = blockIdx.x * 4 + (threadIdx.x >> 6);
  int j = threadIdx.x & 63;
  if (n >= N_NODES) return;
  int jj = (j < DIM_C) ? j : DIM_C;  // lanes >=47 read the zero pad
  int start = row_start[n];
  int deg   = cnt[n];
  float acc0 = h2p[(size_t)n * DIM_CP + jj];  // self term
  float acc1 = 0.f, acc2 = 0.f, acc3 = 0.f;
  int k = 0;
  for (; k + 4 <= deg; k += 4) {
    int s0 = sorted_src[start + k + 0];
    int s1 = sorted_src[start + k + 1];
    int s2 = sorted_src[start + k + 2];
    int s3 = sorted_src[start + k + 3];
    acc0 += h2p[(size_t)s0 * DIM_CP + jj];
    acc1 += h2p[(size_t)s1 * DIM_CP + jj];
    acc2 += h2p[(size_t)s2 * DIM_CP + jj];
    acc3 += h2p[(size_t)s3 * DIM_CP + jj];
  }
  for (; k < deg; ++k)
    acc0 += h2p[(size_t)sorted_src[start + k] * DIM_CP + jj];
  float di = dinv[n];
  float acc = di * ((acc0 + acc1) + (acc2 + acc3)) + ((j < DIM_C) ? b2[jj] : 0.f);

  // fused log_softmax over the 47 classes
  float v = (j < DIM_C) ? acc : -INFINITY;
  float m = v;
  for (int o = 32; o; o >>= 1) m = fmaxf(m, __shfl_xor(m, o));
  float ex = (j < DIM_C) ? __expf(v - m) : 0.0f;
  float s = ex;
  for (int o = 32; o; o >>= 1) s += __shfl_xor(s, o);
  if (j < DIM_C) out[(size_t)n * DIM_C + j] = v - m - __logf(s);
}

extern "C" void kernel_launch(void* const* d_in, const int* in_sizes, int n_in,
                              void* d_out, int out_size, void* d_ws, size_t ws_size,
                              hipStream_t stream) {
  const float* x  = (const float*)d_in[0];
  const float* W1 = (const float*)d_in[1];
  const float* b1 = (const float*)d_in[2];
  const float* W2 = (const float*)d_in[3];
  const float* b2 = (const float*)d_in[4];
  const int*   ei = (const int*)d_in[5];
  const int* src = ei;
  const int* dst = ei + N_EDGES;
  float* out = (float*)d_out;

  float* ws   = (float*)d_ws;
  float* dinv = ws;                                   // N
  float* W2p  = dinv + N_NODES;                       // 64*48
  float* h1s  = W2p + DIM_H * DIM_CP;                 // N*64 (reused for h2p, N*48)
  float* agg1 = h1s + (size_t)N_NODES * DIM_H;        // N*64
  float* h2p  = h1s;                                  // alias: h1s dead after agg1_gather
  int* ibuf       = (int*)(agg1 + (size_t)N_NODES * DIM_H);
  int* cnt        = ibuf;                             // N
  int* cursor     = cnt + N_NODES;                    // N
  int* row_start  = cursor + N_NODES;                 // N
  int* blk_sums   = row_start + N_NODES;              // 128
  int* sorted_src = blk_sums + 128;                   // E

  const int nblk_n  = (N_NODES + 255) / 256;
  const int nblk_e  = (N_EDGES + 255) / 256;
  const int nblk_nw = (N_NODES + 3) / 4;              // wave-per-node gathers
  const int nblk_g  = (N_NODES + 63) / 64;            // 64-row GEMM tiles

  // CSR build + weight pad
  k_zero<<<nblk_n, 256, 0, stream>>>(cnt, cursor);
  k_hist<<<nblk_e, 256, 0, stream>>>(dst, cnt);
  k_dinv<<<nblk_n, 256, 0, stream>>>(cnt, dinv);
  k_padW2<<<(DIM_H * DIM_CP + 255) / 256, 256, 0, stream>>>(W2, W2p);
  k_scan_partial<<<NBLK_SCAN, 256, 0, stream>>>(cnt, row_start, blk_sums);
  k_scan_blk<<<1, 128, 0, stream>>>(blk_sums);
  k_scan_add<<<nblk_n, 256, 0, stream>>>(row_start, blk_sums);
  k_scatter<<<nblk_e, 256, 0, stream>>>(src, dst, row_start, cursor, sorted_src);

  // layer 1
  k_gemm1<<<nblk_g, 256, 0, stream>>>(x, W1, dinv, h1s);
  k_agg1_gather<<<nblk_nw, 256, 0, stream>>>(h1s, dinv, b1, row_start, cnt, sorted_src, agg1);

  // layer 2 (+ fused log_softmax)
  k_gemm2<<<nblk_g, 192, 0, stream>>>(agg1, W2p, dinv, h2p);
  k_agg2_gather<<<nblk_nw, 256, 0, stream>>>(h2p, dinv, b2, row_start, cnt, sorted_src, out);
}

// Round 8
// 383.439 us; speedup vs baseline: 1.6376x; 1.0877x over previous
//
#include <hip/hip_runtime.h>
#include <math.h>

#define N_NODES 100000
#define N_EDGES 1600000
#define DIM_IN  256
#define DIM_H   64
#define DIM_C   47
#define DIM_CP  48                            // padded h2 row stride (192B aligned)
#define SCAN_CHUNK 1024                       // elems per scan block (256 thr x 4)
#define NBLK_SCAN ((N_NODES + SCAN_CHUNK - 1) / SCAN_CHUNK)   // 98
#define NB       8                            // dst buckets (one per XCD)
#define BUCKET_W 12500                        // nodes per bucket
#define BCAP     204000                       // per-bucket capacity (mean 200000 + 9.5 sigma)
#define CHUNK_P1 4096                         // edges per pass-1 block (16/thread)
#define BPB      128                          // pass-2 blocks per bucket

// ---------- zero int buffers ----------
__global__ __launch_bounds__(256) void k_zero(int* __restrict__ cnt,
                                              int* __restrict__ cursor,
                                              int* __restrict__ bucket_cur) {
  int i = blockIdx.x * 256 + threadIdx.x;
  if (i < N_NODES) { cnt[i] = 0; cursor[i] = 0; }
  if (i < NB) bucket_cur[i] = 0;
}

// ---------- pass 1: octant binning + fused per-node degree histogram ----------
// Block reads CHUNK_P1 contiguous edges, bins into 8 dst-octants. Per-block
// bucket sub-regions are contiguous (one global atomicAdd per bucket) so the
// packed writes are line-dense -- this is what kills the 17x write amp of the
// single-pass scatter (R6: WRITE_SIZE 107MB for 6.4MB payload).
__global__ __launch_bounds__(256) void k_bin(const int* __restrict__ src,
                                             const int* __restrict__ dst,
                                             int* __restrict__ cnt,
                                             int* __restrict__ bucket_cur,
                                             unsigned* __restrict__ bucket_buf) {
  __shared__ int lcnt[NB], lbase[NB], lcur[NB];
  if (threadIdx.x < NB) lcnt[threadIdx.x] = 0;
  __syncthreads();
  const int base = blockIdx.x * CHUNK_P1 + threadIdx.x;
  int dreg[16], sreg[16];
#pragma unroll
  for (int it = 0; it < 16; ++it) {
    int e = base + it * 256;
    int d = -1, s = 0;
    if (e < N_EDGES) { d = dst[e]; s = src[e]; }
    dreg[it] = d; sreg[it] = s;
    if (d >= 0) {
      atomicAdd(&lcnt[d / BUCKET_W], 1);
      atomicAdd(&cnt[d], 1);          // degree histogram (replaces k_hist)
    }
  }
  __syncthreads();
  if (threadIdx.x < NB) {
    lbase[threadIdx.x] = atomicAdd(&bucket_cur[threadIdx.x], lcnt[threadIdx.x]);
    lcur[threadIdx.x] = 0;
  }
  __syncthreads();
#pragma unroll
  for (int it = 0; it < 16; ++it) {
    int d = dreg[it];
    if (d >= 0) {
      int b = d / BUCKET_W;
      int r = atomicAdd(&lcur[b], 1);
      unsigned pack = ((unsigned)(d - b * BUCKET_W) << 17) | (unsigned)sreg[it];
      bucket_buf[(size_t)b * BCAP + lbase[b] + r] = pack;
    }
  }
}

// ---------- dinv = rsqrt(deg+1)  (self-loop) ----------
__global__ __launch_bounds__(256) void k_dinv(const int* __restrict__ cnt,
                                              float* __restrict__ dinv) {
  int i = blockIdx.x * 256 + threadIdx.x;
  if (i < N_NODES) dinv[i] = rsqrtf((float)cnt[i] + 1.0f);
}

// ---------- pad W2 (64x47) into W2p (64x48, zero pad col) ----------
__global__ __launch_bounds__(256) void k_padW2(const float* __restrict__ W2,
                                               float* __restrict__ W2p) {
  int i = blockIdx.x * 256 + threadIdx.x;
  if (i >= DIM_H * DIM_CP) return;
  int k = i / DIM_CP, j = i % DIM_CP;
  W2p[i] = (j < DIM_C) ? W2[k * DIM_C + j] : 0.f;
}

// ---------- exclusive scan of cnt -> row_start (3 kernels) ----------
__global__ __launch_bounds__(256) void k_scan_partial(const int* __restrict__ cnt,
                                                      int* __restrict__ row_start,
                                                      int* __restrict__ blk_sums) {
  __shared__ int ls[256];
  const int tid  = threadIdx.x;
  const int base = blockIdx.x * SCAN_CHUNK + tid * 4;
  int c0 = (base + 0 < N_NODES) ? cnt[base + 0] : 0;
  int c1 = (base + 1 < N_NODES) ? cnt[base + 1] : 0;
  int c2 = (base + 2 < N_NODES) ? cnt[base + 2] : 0;
  int c3 = (base + 3 < N_NODES) ? cnt[base + 3] : 0;
  int tsum = c0 + c1 + c2 + c3;
  ls[tid] = tsum;
  __syncthreads();
  for (int off = 1; off < 256; off <<= 1) {
    int v = (tid >= off) ? ls[tid - off] : 0;
    __syncthreads();
    ls[tid] += v;
    __syncthreads();
  }
  int excl = ls[tid] - tsum;
  if (base + 0 < N_NODES) row_start[base + 0] = excl;
  if (base + 1 < N_NODES) row_start[base + 1] = excl + c0;
  if (base + 2 < N_NODES) row_start[base + 2] = excl + c0 + c1;
  if (base + 3 < N_NODES) row_start[base + 3] = excl + c0 + c1 + c2;
  if (tid == 255) blk_sums[blockIdx.x] = ls[255];
}

__global__ __launch_bounds__(128) void k_scan_blk(int* __restrict__ blk_sums) {
  __shared__ int ls[128];
  const int tid = threadIdx.x;
  int v = (tid < NBLK_SCAN) ? blk_sums[tid] : 0;
  ls[tid] = v;
  __syncthreads();
  for (int off = 1; off < 128; off <<= 1) {
    int u = (tid >= off) ? ls[tid - off] : 0;
    __syncthreads();
    ls[tid] += u;
    __syncthreads();
  }
  if (tid < NBLK_SCAN) blk_sums[tid] = ls[tid] - v;
}

__global__ __launch_bounds__(256) void k_scan_add(int* __restrict__ row_start,
                                                  const int* __restrict__ blk_sums) {
  int i = blockIdx.x * 256 + threadIdx.x;
  if (i < N_NODES) row_start[i] += blk_sums[i / SCAN_CHUNK];
}

// ---------- pass 2: per-bucket fine scatter ----------
// bucket = blockIdx & 7: with round-robin blockIdx->XCD dispatch each octant's
// 0.8MB scatter region stays in ONE XCD's L2 -> lines fill before eviction.
__global__ __launch_bounds__(256) void k_scatter2(const unsigned* __restrict__ bucket_buf,
                                                  const int* __restrict__ bucket_cnt,
                                                  const int* __restrict__ row_start,
                                                  int* __restrict__ cursor,
                                                  int* __restrict__ sorted_src) {
  const int b   = blockIdx.x & (NB - 1);
  const int sub = blockIdx.x >> 3;
  const int n_b = bucket_cnt[b];
  const unsigned* buf = bucket_buf + (size_t)b * BCAP;
  for (int i = sub * 256 + (int)threadIdx.x; i < n_b; i += BPB * 256) {
    unsigned pack = buf[i];
    int s = (int)(pack & 0x1FFFFu);
    int d = b * BUCKET_W + (int)(pack >> 17);
    int pos = row_start[d] + atomicAdd(&cursor[d], 1);
    sorted_src[pos] = s;
  }
}

// ---------- layer 1 GEMM + dinv pre-scale: h1s = dinv[n] * (x @ W1) ----------
// Block = 4 waves x 64 lanes = one 64-row tile. Wave w -> cols [16w,16w+16);
// lane -> row. j0 forced into SGPR via readfirstlane so W reads stay s_load.
__global__ __launch_bounds__(256) void k_gemm1(const float* __restrict__ x,
                                               const float* __restrict__ W,
                                               const float* __restrict__ dinv,
                                               float* __restrict__ h1s) {
  const int lane = threadIdx.x & 63;
  const int j0   = __builtin_amdgcn_readfirstlane((threadIdx.x >> 6) * 16);
  int row = blockIdx.x * 64 + lane;
  if (row >= N_NODES) row = N_NODES - 1;  // clamp: duplicate work, identical values
  const float4* xr = (const float4*)(x + (size_t)row * DIM_IN);

  float acc[16];
#pragma unroll
  for (int j = 0; j < 16; ++j) acc[j] = 0.f;

#pragma unroll 1
  for (int k4 = 0; k4 < DIM_IN / 4; ++k4) {
    float4 xv = xr[k4];
#pragma unroll
    for (int kk = 0; kk < 4; ++kk) {
      float xk = (kk == 0) ? xv.x : (kk == 1) ? xv.y : (kk == 2) ? xv.z : xv.w;
      const float* wrow = W + (size_t)(4 * k4 + kk) * DIM_H + j0;  // uniform -> s_load
#pragma unroll
      for (int j = 0; j < 16; ++j)
        acc[j] = fmaf(xk, wrow[j], acc[j]);
    }
  }

  float di = dinv[row];
  float4* out = (float4*)(h1s + (size_t)row * DIM_H + j0);
#pragma unroll
  for (int j4 = 0; j4 < 4; ++j4)
    out[j4] = make_float4(di * acc[4 * j4], di * acc[4 * j4 + 1],
                          di * acc[4 * j4 + 2], di * acc[4 * j4 + 3]);
}

// ---------- agg1 gather: wave per node, lane = channel, 4-way unrolled CSR loop ----------
__global__ __launch_bounds__(256) void k_agg1_gather(const float* __restrict__ h1s,
                                                     const float* __restrict__ dinv,
                                                     const float* __restrict__ b1,
                                                     const int* __restrict__ row_start,
                                                     const int* __restrict__ cnt,
                                                     const int* __restrict__ sorted_src,
                                                     float* __restrict__ agg1) {
  int n = blockIdx.x * 4 + (threadIdx.x >> 6);
  int j = threadIdx.x & 63;
  if (n >= N_NODES) return;
  int start = row_start[n];
  int deg   = cnt[n];
  float acc0 = h1s[(size_t)n * DIM_H + j];  // self term
  float acc1 = 0.f, acc2 = 0.f, acc3 = 0.f;
  int k = 0;
  for (; k + 4 <= deg; k += 4) {
    int s0 = sorted_src[start + k + 0];
    int s1 = sorted_src[start + k + 1];
    int s2 = sorted_src[start + k + 2];
    int s3 = sorted_src[start + k + 3];
    acc0 += h1s[(size_t)s0 * DIM_H + j];
    acc1 += h1s[(size_t)s1 * DIM_H + j];
    acc2 += h1s[(size_t)s2 * DIM_H + j];
    acc3 += h1s[(size_t)s3 * DIM_H + j];
  }
  for (; k < deg; ++k)
    acc0 += h1s[(size_t)sorted_src[start + k] * DIM_H + j];
  float di = dinv[n];
  agg1[(size_t)n * DIM_H + j] = di * ((acc0 + acc1) + (acc2 + acc3)) + b1[j];
}

// ---------- layer 2 GEMM + ReLU + dinv pre-scale: h2p = dinv[n]*(relu(agg1) @ W2p) ----------
__global__ __launch_bounds__(192) void k_gemm2(const float* __restrict__ agg1,
                                               const float* __restrict__ W2p,
                                               const float* __restrict__ dinv,
                                               float* __restrict__ h2p) {
  const int lane = threadIdx.x & 63;
  const int j0   = __builtin_amdgcn_readfirstlane((threadIdx.x >> 6) * 16);
  int row = blockIdx.x * 64 + lane;
  if (row >= N_NODES) row = N_NODES - 1;
  const float4* xr = (const float4*)(agg1 + (size_t)row * DIM_H);

  float acc[16];
#pragma unroll
  for (int j = 0; j < 16; ++j) acc[j] = 0.f;

#pragma unroll 1
  for (int k4 = 0; k4 < DIM_H / 4; ++k4) {
    float4 xv = xr[k4];
    xv.x = fmaxf(xv.x, 0.f); xv.y = fmaxf(xv.y, 0.f);
    xv.z = fmaxf(xv.z, 0.f); xv.w = fmaxf(xv.w, 0.f);
#pragma unroll
    for (int kk = 0; kk < 4; ++kk) {
      float xk = (kk == 0) ? xv.x : (kk == 1) ? xv.y : (kk == 2) ? xv.z : xv.w;
      const float* wrow = W2p + (size_t)(4 * k4 + kk) * DIM_CP + j0;  // uniform -> s_load
#pragma unroll
      for (int j = 0; j < 16; ++j)
        acc[j] = fmaf(xk, wrow[j], acc[j]);
    }
  }

  float di = dinv[row];
  float4* out = (float4*)(h2p + (size_t)row * DIM_CP + j0);
#pragma unroll
  for (int j4 = 0; j4 < 4; ++j4)
    out[j4] = make_float4(di * acc[4 * j4], di * acc[4 * j4 + 1],
                          di * acc[4 * j4 + 2], di * acc[4 * j4 + 3]);
}

// ---------- agg2 gather + fused log_softmax: wave per node, 4-way unrolled ----------
__global__ __launch_bounds__(256) void k_agg2_gather(const float* __restrict__ h2p,
                                                     const float* __restrict__ dinv,
                                                     const float* __restrict__ b2,
                                                     const int* __restrict__ row_start,
                                                     const int* __restrict__ cnt,
                                                     const int* __restrict__ sorted_src,
                                                     float* __restrict__ out) {
  int n = blockIdx.x * 4 + (threadIdx.x >> 6);
  int j = threadIdx.x & 63;
  if (n >= N_NODES) return;
  int jj = (j < DIM_C) ? j : DIM_C;  // lanes >=47 read the zero pad
  int start = row_start[n];
  int deg   = cnt[n];
  float acc0 = h2p[(size_t)n * DIM_CP + jj];  // self term
  float acc1 = 0.f, acc2 = 0.f, acc3 = 0.f;
  int k = 0;
  for (; k + 4 <= deg; k += 4) {
    int s0 = sorted_src[start + k + 0];
    int s1 = sorted_src[start + k + 1];
    int s2 = sorted_src[start + k + 2];
    int s3 = sorted_src[start + k + 3];
    acc0 += h2p[(size_t)s0 * DIM_CP + jj];
    acc1 += h2p[(size_t)s1 * DIM_CP + jj];
    acc2 += h2p[(size_t)s2 * DIM_CP + jj];
    acc3 += h2p[(size_t)s3 * DIM_CP + jj];
  }
  for (; k < deg; ++k)
    acc0 += h2p[(size_t)sorted_src[start + k] * DIM_CP + jj];
  float di = dinv[n];
  float acc = di * ((acc0 + acc1) + (acc2 + acc3)) + ((j < DIM_C) ? b2[jj] : 0.f);

  // fused log_softmax over the 47 classes
  float v = (j < DIM_C) ? acc : -INFINITY;
  float m = v;
  for (int o = 32; o; o >>= 1) m = fmaxf(m, __shfl_xor(m, o));
  float ex = (j < DIM_C) ? __expf(v - m) : 0.0f;
  float s = ex;
  for (int o = 32; o; o >>= 1) s += __shfl_xor(s, o);
  if (j < DIM_C) out[(size_t)n * DIM_C + j] = v - m - __logf(s);
}

extern "C" void kernel_launch(void* const* d_in, const int* in_sizes, int n_in,
                              void* d_out, int out_size, void* d_ws, size_t ws_size,
                              hipStream_t stream) {
  const float* x  = (const float*)d_in[0];
  const float* W1 = (const float*)d_in[1];
  const float* b1 = (const float*)d_in[2];
  const float* W2 = (const float*)d_in[3];
  const float* b2 = (const float*)d_in[4];
  const int*   ei = (const int*)d_in[5];
  const int* src = ei;
  const int* dst = ei + N_EDGES;
  float* out = (float*)d_out;

  float* ws   = (float*)d_ws;
  float* dinv = ws;                                   // N
  float* W2p  = dinv + N_NODES;                       // 64*48
  float* h1s  = W2p + DIM_H * DIM_CP;                 // N*64 (reused for h2p, N*48)
  float* agg1 = h1s + (size_t)N_NODES * DIM_H;        // N*64
  float* h2p  = h1s;                                  // alias: h1s dead after agg1_gather
  int* ibuf        = (int*)(agg1 + (size_t)N_NODES * DIM_H);
  int* cnt         = ibuf;                            // N
  int* cursor      = cnt + N_NODES;                   // N
  int* row_start   = cursor + N_NODES;                // N
  int* blk_sums    = row_start + N_NODES;             // 128
  int* bucket_cur  = blk_sums + 128;                  // 8 (+pad)
  int* sorted_src  = bucket_cur + 64;                 // E
  unsigned* bucket_buf = (unsigned*)(sorted_src + N_EDGES);  // NB*BCAP

  const int nblk_n  = (N_NODES + 255) / 256;
  const int nblk_nw = (N_NODES + 3) / 4;              // wave-per-node gathers
  const int nblk_g  = (N_NODES + 63) / 64;            // 64-row GEMM tiles
  const int nblk_p1 = (N_EDGES + CHUNK_P1 - 1) / CHUNK_P1;

  // CSR build (two-pass bucket sort) + weight pad
  k_zero<<<nblk_n, 256, 0, stream>>>(cnt, cursor, bucket_cur);
  k_bin<<<nblk_p1, 256, 0, stream>>>(src, dst, cnt, bucket_cur, bucket_buf);
  k_dinv<<<nblk_n, 256, 0, stream>>>(cnt, dinv);
  k_padW2<<<(DIM_H * DIM_CP + 255) / 256, 256, 0, stream>>>(W2, W2p);
  k_scan_partial<<<NBLK_SCAN, 256, 0, stream>>>(cnt, row_start, blk_sums);
  k_scan_blk<<<1, 128, 0, stream>>>(blk_sums);
  k_scan_add<<<nblk_n, 256, 0, stream>>>(row_start, blk_sums);
  k_scatter2<<<NB * BPB, 256, 0, stream>>>(bucket_buf, bucket_cur, row_start, cursor, sorted_src);

  // layer 1
  k_gemm1<<<nblk_g, 256, 0, stream>>>(x, W1, dinv, h1s);
  k_agg1_gather<<<nblk_nw, 256, 0, stream>>>(h1s, dinv, b1, row_start, cnt, sorted_src, agg1);

  // layer 2 (+ fused log_softmax)
  k_gemm2<<<nblk_g, 192, 0, stream>>>(agg1, W2p, dinv, h2p);
  k_agg2_gather<<<nblk_nw, 256, 0, stream>>>(h2p, dinv, b2, row_start, cnt, sorted_src, out);
}

// Round 9
// 365.709 us; speedup vs baseline: 1.7170x; 1.0485x over previous
//
#include <hip/hip_runtime.h>
#include <math.h>

#define N_NODES 100000
#define N_EDGES 1600000
#define DIM_IN  256
#define DIM_H   64
#define DIM_C   47
#define DIM_CP  48                            // padded h2 row stride (192B aligned)
#define SCAN_CHUNK 1024                       // elems per scan block (256 thr x 4)
#define NBLK_SCAN ((N_NODES + SCAN_CHUNK - 1) / SCAN_CHUNK)   // 98
#define NB       8                            // dst buckets (one per XCD)
#define BUCKET_W 12500                        // nodes per bucket
#define BCAP     204000                       // per-bucket capacity
#define CHUNK_P1 4096                         // edges per pass-1 block (16/thread)
#define BPB      128                          // pass-2 blocks per bucket

typedef __attribute__((ext_vector_type(8))) short bf16x8;
typedef __attribute__((ext_vector_type(4))) float f32x4;

// RNE float -> bf16 bits (avoids header-struct dependence)
static __device__ __forceinline__ short f2bf(float f) {
  unsigned u = __builtin_bit_cast(unsigned, f);
  u += 0x7FFFu + ((u >> 16) & 1u);
  return (short)(u >> 16);
}

// ---------- zero int buffers ----------
__global__ __launch_bounds__(256) void k_zero(int* __restrict__ cnt,
                                              int* __restrict__ cursor,
                                              int* __restrict__ bucket_cur) {
  int i = blockIdx.x * 256 + threadIdx.x;
  if (i < N_NODES) { cnt[i] = 0; cursor[i] = 0; }
  if (i < NB) bucket_cur[i] = 0;
}

// ---------- pass 1: octant binning + fused per-node degree histogram ----------
__global__ __launch_bounds__(256) void k_bin(const int* __restrict__ src,
                                             const int* __restrict__ dst,
                                             int* __restrict__ cnt,
                                             int* __restrict__ bucket_cur,
                                             unsigned* __restrict__ bucket_buf) {
  __shared__ int lcnt[NB], lbase[NB], lcur[NB];
  if (threadIdx.x < NB) lcnt[threadIdx.x] = 0;
  __syncthreads();
  const int base = blockIdx.x * CHUNK_P1 + threadIdx.x;
  int dreg[16], sreg[16];
#pragma unroll
  for (int it = 0; it < 16; ++it) {
    int e = base + it * 256;
    int d = -1, s = 0;
    if (e < N_EDGES) { d = dst[e]; s = src[e]; }
    dreg[it] = d; sreg[it] = s;
    if (d >= 0) {
      atomicAdd(&lcnt[d / BUCKET_W], 1);
      atomicAdd(&cnt[d], 1);          // degree histogram
    }
  }
  __syncthreads();
  if (threadIdx.x < NB) {
    lbase[threadIdx.x] = atomicAdd(&bucket_cur[threadIdx.x], lcnt[threadIdx.x]);
    lcur[threadIdx.x] = 0;
  }
  __syncthreads();
#pragma unroll
  for (int it = 0; it < 16; ++it) {
    int d = dreg[it];
    if (d >= 0) {
      int b = d / BUCKET_W;
      int r = atomicAdd(&lcur[b], 1);
      unsigned pack = ((unsigned)(d - b * BUCKET_W) << 17) | (unsigned)sreg[it];
      bucket_buf[(size_t)b * BCAP + lbase[b] + r] = pack;
    }
  }
}

// ---------- dinv = rsqrt(deg+1) ----------
__global__ __launch_bounds__(256) void k_dinv(const int* __restrict__ cnt,
                                              float* __restrict__ dinv) {
  int i = blockIdx.x * 256 + threadIdx.x;
  if (i < N_NODES) dinv[i] = rsqrtf((float)cnt[i] + 1.0f);
}

// ---------- pad W2 (64x47) into W2p (64x48) ----------
__global__ __launch_bounds__(256) void k_padW2(const float* __restrict__ W2,
                                               float* __restrict__ W2p) {
  int i = blockIdx.x * 256 + threadIdx.x;
  if (i >= DIM_H * DIM_CP) return;
  int k = i / DIM_CP, j = i % DIM_CP;
  W2p[i] = (j < DIM_C) ? W2[k * DIM_C + j] : 0.f;
}

// ---------- pre-swizzle W1 into per-lane MFMA B-fragment order ----------
// idx = ((wv*8 + ks)*64 + lane)*8 + e ; B[k][n]: n = wv*16+(lane&15),
// k = ks*32 + (lane>>4)*8 + e  (16x16x32 bf16 operand layout)
__global__ __launch_bounds__(256) void k_prepW1(const float* __restrict__ W1,
                                                short* __restrict__ W1f) {
  int i = blockIdx.x * 256 + threadIdx.x;
  if (i >= 4 * 8 * 64 * 8) return;
  int e    = i & 7;
  int lane = (i >> 3) & 63;
  int ks   = (i >> 9) & 7;
  int wv   = i >> 12;
  int col  = wv * 16 + (lane & 15);
  int k    = ks * 32 + (lane >> 4) * 8 + e;
  W1f[i] = f2bf(W1[k * DIM_H + col]);
}

// ---------- exclusive scan of cnt -> row_start ----------
__global__ __launch_bounds__(256) void k_scan_partial(const int* __restrict__ cnt,
                                                      int* __restrict__ row_start,
                                                      int* __restrict__ blk_sums) {
  __shared__ int ls[256];
  const int tid  = threadIdx.x;
  const int base = blockIdx.x * SCAN_CHUNK + tid * 4;
  int c0 = (base + 0 < N_NODES) ? cnt[base + 0] : 0;
  int c1 = (base + 1 < N_NODES) ? cnt[base + 1] : 0;
  int c2 = (base + 2 < N_NODES) ? cnt[base + 2] : 0;
  int c3 = (base + 3 < N_NODES) ? cnt[base + 3] : 0;
  int tsum = c0 + c1 + c2 + c3;
  ls[tid] = tsum;
  __syncthreads();
  for (int off = 1; off < 256; off <<= 1) {
    int v = (tid >= off) ? ls[tid - off] : 0;
    __syncthreads();
    ls[tid] += v;
    __syncthreads();
  }
  int excl = ls[tid] - tsum;
  if (base + 0 < N_NODES) row_start[base + 0] = excl;
  if (base + 1 < N_NODES) row_start[base + 1] = excl + c0;
  if (base + 2 < N_NODES) row_start[base + 2] = excl + c0 + c1;
  if (base + 3 < N_NODES) row_start[base + 3] = excl + c0 + c1 + c2;
  if (tid == 255) blk_sums[blockIdx.x] = ls[255];
}

__global__ __launch_bounds__(128) void k_scan_blk(int* __restrict__ blk_sums) {
  __shared__ int ls[128];
  const int tid = threadIdx.x;
  int v = (tid < NBLK_SCAN) ? blk_sums[tid] : 0;
  ls[tid] = v;
  __syncthreads();
  for (int off = 1; off < 128; off <<= 1) {
    int u = (tid >= off) ? ls[tid - off] : 0;
    __syncthreads();
    ls[tid] += u;
    __syncthreads();
  }
  if (tid < NBLK_SCAN) blk_sums[tid] = ls[tid] - v;
}

__global__ __launch_bounds__(256) void k_scan_add(int* __restrict__ row_start,
                                                  const int* __restrict__ blk_sums) {
  int i = blockIdx.x * 256 + threadIdx.x;
  if (i < N_NODES) row_start[i] += blk_sums[i / SCAN_CHUNK];
}

// ---------- pass 2: per-bucket fine scatter ----------
__global__ __launch_bounds__(256) void k_scatter2(const unsigned* __restrict__ bucket_buf,
                                                  const int* __restrict__ bucket_cnt,
                                                  const int* __restrict__ row_start,
                                                  int* __restrict__ cursor,
                                                  int* __restrict__ sorted_src) {
  const int b   = blockIdx.x & (NB - 1);
  const int sub = blockIdx.x >> 3;
  const int n_b = bucket_cnt[b];
  const unsigned* buf = bucket_buf + (size_t)b * BCAP;
  for (int i = sub * 256 + (int)threadIdx.x; i < n_b; i += BPB * 256) {
    unsigned pack = buf[i];
    int s = (int)(pack & 0x1FFFFu);
    int d = b * BUCKET_W + (int)(pack >> 17);
    int pos = row_start[d] + atomicAdd(&cursor[d], 1);
    sorted_src[pos] = s;
  }
}

// ---------- layer 1 GEMM on matrix cores: h1s = dinv[n] * (x @ W1) ----------
// Block = 4 waves; block tile = 16 rows x 64 cols; wave wv -> cols [16wv,16wv+16).
// 8x mfma_f32_16x16x32_bf16 chained over K=256. A converted f32->bf16 in-register;
// B read pre-swizzled (k_prepW1). C/D: col=lane&15, row=(lane>>4)*4+reg (m89 layout).
__global__ __launch_bounds__(256) void k_gemm1(const float* __restrict__ x,
                                               const short* __restrict__ W1f,
                                               const float* __restrict__ dinv,
                                               float* __restrict__ h1s) {
  const int lane = threadIdx.x & 63;
  const int wv   = threadIdx.x >> 6;
  const int m16  = lane & 15;
  const int kb   = lane >> 4;                 // 0..3
  const int base_row = blockIdx.x * 16;       // 100000 % 16 == 0
  const float* xp = x + (size_t)(base_row + m16) * DIM_IN + kb * 8;
  const bf16x8* wf = (const bf16x8*)W1f + (size_t)wv * 8 * 64 + lane;

  f32x4 c = {0.f, 0.f, 0.f, 0.f};
#pragma unroll
  for (int ks = 0; ks < 8; ++ks) {
    float4 a0 = *(const float4*)(xp + ks * 32);
    float4 a1 = *(const float4*)(xp + ks * 32 + 4);
    bf16x8 af;
    af[0] = f2bf(a0.x); af[1] = f2bf(a0.y); af[2] = f2bf(a0.z); af[3] = f2bf(a0.w);
    af[4] = f2bf(a1.x); af[5] = f2bf(a1.y); af[6] = f2bf(a1.z); af[7] = f2bf(a1.w);
    bf16x8 bf = wf[ks * 64];
    c = __builtin_amdgcn_mfma_f32_16x16x32_bf16(af, bf, c, 0, 0, 0);
  }

  const int j0 = wv * 16 + m16;               // output column
#pragma unroll
  for (int r = 0; r < 4; ++r) {
    int row = base_row + kb * 4 + r;
    h1s[(size_t)row * DIM_H + j0] = c[r] * dinv[row];
  }
}

// ---------- agg1 gather: wave per node, lane = channel, 8-way unrolled ----------
__global__ __launch_bounds__(256) void k_agg1_gather(const float* __restrict__ h1s,
                                                     const float* __restrict__ dinv,
                                                     const float* __restrict__ b1,
                                                     const int* __restrict__ row_start,
                                                     const int* __restrict__ cnt,
                                                     const int* __restrict__ sorted_src,
                                                     float* __restrict__ agg1) {
  int n = blockIdx.x * 4 + (threadIdx.x >> 6);
  int j = threadIdx.x & 63;
  if (n >= N_NODES) return;
  int start = row_start[n];
  int deg   = cnt[n];
  float acc0 = h1s[(size_t)n * DIM_H + j];  // self term
  float acc1 = 0.f, acc2 = 0.f, acc3 = 0.f;
  float acc4 = 0.f, acc5 = 0.f, acc6 = 0.f, acc7 = 0.f;
  int k = 0;
  for (; k + 8 <= deg; k += 8) {
    int s0 = sorted_src[start + k + 0];
    int s1 = sorted_src[start + k + 1];
    int s2 = sorted_src[start + k + 2];
    int s3 = sorted_src[start + k + 3];
    int s4 = sorted_src[start + k + 4];
    int s5 = sorted_src[start + k + 5];
    int s6 = sorted_src[start + k + 6];
    int s7 = sorted_src[start + k + 7];
    acc0 += h1s[(size_t)s0 * DIM_H + j];
    acc1 += h1s[(size_t)s1 * DIM_H + j];
    acc2 += h1s[(size_t)s2 * DIM_H + j];
    acc3 += h1s[(size_t)s3 * DIM_H + j];
    acc4 += h1s[(size_t)s4 * DIM_H + j];
    acc5 += h1s[(size_t)s5 * DIM_H + j];
    acc6 += h1s[(size_t)s6 * DIM_H + j];
    acc7 += h1s[(size_t)s7 * DIM_H + j];
  }
  for (; k + 2 <= deg; k += 2) {
    int s0 = sorted_src[start + k + 0];
    int s1 = sorted_src[start + k + 1];
    acc0 += h1s[(size_t)s0 * DIM_H + j];
    acc1 += h1s[(size_t)s1 * DIM_H + j];
  }
  for (; k < deg; ++k)
    acc0 += h1s[(size_t)sorted_src[start + k] * DIM_H + j];
  float di = dinv[n];
  agg1[(size_t)n * DIM_H + j] =
      di * (((acc0 + acc1) + (acc2 + acc3)) + ((acc4 + acc5) + (acc6 + acc7))) + b1[j];
}

// ---------- layer 2 GEMM + ReLU + dinv pre-scale (fp32) ----------
__global__ __launch_bounds__(192) void k_gemm2(const float* __restrict__ agg1,
                                               const float* __restrict__ W2p,
                                               const float* __restrict__ dinv,
                                               float* __restrict__ h2p) {
  const int lane = threadIdx.x & 63;
  const int j0   = __builtin_amdgcn_readfirstlane((threadIdx.x >> 6) * 16);
  int row = blockIdx.x * 64 + lane;
  if (row >= N_NODES) row = N_NODES - 1;
  const float4* xr = (const float4*)(agg1 + (size_t)row * DIM_H);

  float acc[16];
#pragma unroll
  for (int j = 0; j < 16; ++j) acc[j] = 0.f;

#pragma unroll 1
  for (int k4 = 0; k4 < DIM_H / 4; ++k4) {
    float4 xv = xr[k4];
    xv.x = fmaxf(xv.x, 0.f); xv.y = fmaxf(xv.y, 0.f);
    xv.z = fmaxf(xv.z, 0.f); xv.w = fmaxf(xv.w, 0.f);
#pragma unroll
    for (int kk = 0; kk < 4; ++kk) {
      float xk = (kk == 0) ? xv.x : (kk == 1) ? xv.y : (kk == 2) ? xv.z : xv.w;
      const float* wrow = W2p + (size_t)(4 * k4 + kk) * DIM_CP + j0;  // uniform -> s_load
#pragma unroll
      for (int j = 0; j < 16; ++j)
        acc[j] = fmaf(xk, wrow[j], acc[j]);
    }
  }

  float di = dinv[row];
  float4* out = (float4*)(h2p + (size_t)row * DIM_CP + j0);
#pragma unroll
  for (int j4 = 0; j4 < 4; ++j4)
    out[j4] = make_float4(di * acc[4 * j4], di * acc[4 * j4 + 1],
                          di * acc[4 * j4 + 2], di * acc[4 * j4 + 3]);
}

// ---------- agg2 gather + fused log_softmax: wave per node, 8-way unrolled ----------
__global__ __launch_bounds__(256) void k_agg2_gather(const float* __restrict__ h2p,
                                                     const float* __restrict__ dinv,
                                                     const float* __restrict__ b2,
                                                     const int* __restrict__ row_start,
                                                     const int* __restrict__ cnt,
                                                     const int* __restrict__ sorted_src,
                                                     float* __restrict__ out) {
  int n = blockIdx.x * 4 + (threadIdx.x >> 6);
  int j = threadIdx.x & 63;
  if (n >= N_NODES) return;
  int jj = (j < DIM_C) ? j : DIM_C;  // lanes >=47 read the zero pad
  int start = row_start[n];
  int deg   = cnt[n];
  float acc0 = h2p[(size_t)n * DIM_CP + jj];  // self term
  float acc1 = 0.f, acc2 = 0.f, acc3 = 0.f;
  float acc4 = 0.f, acc5 = 0.f, acc6 = 0.f, acc7 = 0.f;
  int k = 0;
  for (; k + 8 <= deg; k += 8) {
    int s0 = sorted_src[start + k + 0];
    int s1 = sorted_src[start + k + 1];
    int s2 = sorted_src[start + k + 2];
    int s3 = sorted_src[start + k + 3];
    int s4 = sorted_src[start + k + 4];
    int s5 = sorted_src[start + k + 5];
    int s6 = sorted_src[start + k + 6];
    int s7 = sorted_src[start + k + 7];
    acc0 += h2p[(size_t)s0 * DIM_CP + jj];
    acc1 += h2p[(size_t)s1 * DIM_CP + jj];
    acc2 += h2p[(size_t)s2 * DIM_CP + jj];
    acc3 += h2p[(size_t)s3 * DIM_CP + jj];
    acc4 += h2p[(size_t)s4 * DIM_CP + jj];
    acc5 += h2p[(size_t)s5 * DIM_CP + jj];
    acc6 += h2p[(size_t)s6 * DIM_CP + jj];
    acc7 += h2p[(size_t)s7 * DIM_CP + jj];
  }
  for (; k + 2 <= deg; k += 2) {
    int s0 = sorted_src[start + k + 0];
    int s1 = sorted_src[start + k + 1];
    acc0 += h2p[(size_t)s0 * DIM_CP + jj];
    acc1 += h2p[(size_t)s1 * DIM_CP + jj];
  }
  for (; k < deg; ++k)
    acc0 += h2p[(size_t)sorted_src[start + k] * DIM_CP + jj];
  float di = dinv[n];
  float acc = di * (((acc0 + acc1) + (acc2 + acc3)) + ((acc4 + acc5) + (acc6 + acc7)))
            + ((j < DIM_C) ? b2[jj] : 0.f);

  // fused log_softmax over the 47 classes
  float v = (j < DIM_C) ? acc : -INFINITY;
  float m = v;
  for (int o = 32; o; o >>= 1) m = fmaxf(m, __shfl_xor(m, o));
  float ex = (j < DIM_C) ? __expf(v - m) : 0.0f;
  float s = ex;
  for (int o = 32; o; o >>= 1) s += __shfl_xor(s, o);
  if (j < DIM_C) out[(size_t)n * DIM_C + j] = v - m - __logf(s);
}

extern "C" void kernel_launch(void* const* d_in, const int* in_sizes, int n_in,
                              void* d_out, int out_size, void* d_ws, size_t ws_size,
                              hipStream_t stream) {
  const float* x  = (const float*)d_in[0];
  const float* W1 = (const float*)d_in[1];
  const float* b1 = (const float*)d_in[2];
  const float* W2 = (const float*)d_in[3];
  const float* b2 = (const float*)d_in[4];
  const int*   ei = (const int*)d_in[5];
  const int* src = ei;
  const int* dst = ei + N_EDGES;
  float* out = (float*)d_out;

  float* ws   = (float*)d_ws;
  float* dinv = ws;                                   // N
  float* W2p  = dinv + N_NODES;                       // 64*48
  short* W1f  = (short*)(W2p + DIM_H * DIM_CP);       // 16384 shorts (8192 floats)
  float* h1s  = (float*)(W1f + 4 * 8 * 64 * 8);       // N*64 (reused for h2p, N*48)
  float* agg1 = h1s + (size_t)N_NODES * DIM_H;        // N*64
  float* h2p  = h1s;                                  // alias: h1s dead after agg1_gather
  int* ibuf        = (int*)(agg1 + (size_t)N_NODES * DIM_H);
  int* cnt         = ibuf;                            // N
  int* cursor      = cnt + N_NODES;                   // N
  int* row_start   = cursor + N_NODES;                // N
  int* blk_sums    = row_start + N_NODES;             // 128
  int* bucket_cur  = blk_sums + 128;                  // 8 (+pad)
  int* sorted_src  = bucket_cur + 64;                 // E
  unsigned* bucket_buf = (unsigned*)(sorted_src + N_EDGES);  // NB*BCAP

  const int nblk_n  = (N_NODES + 255) / 256;
  const int nblk_nw = (N_NODES + 3) / 4;              // wave-per-node gathers
  const int nblk_g1 = N_NODES / 16;                   // 6250 MFMA tiles
  const int nblk_g2 = (N_NODES + 63) / 64;            // fp32 gemm2 tiles
  const int nblk_p1 = (N_EDGES + CHUNK_P1 - 1) / CHUNK_P1;

  // CSR build (two-pass bucket sort) + weight prep
  k_zero<<<nblk_n, 256, 0, stream>>>(cnt, cursor, bucket_cur);
  k_bin<<<nblk_p1, 256, 0, stream>>>(src, dst, cnt, bucket_cur, bucket_buf);
  k_dinv<<<nblk_n, 256, 0, stream>>>(cnt, dinv);
  k_padW2<<<(DIM_H * DIM_CP + 255) / 256, 256, 0, stream>>>(W2, W2p);
  k_prepW1<<<64, 256, 0, stream>>>(W1, W1f);
  k_scan_partial<<<NBLK_SCAN, 256, 0, stream>>>(cnt, row_start, blk_sums);
  k_scan_blk<<<1, 128, 0, stream>>>(blk_sums);
  k_scan_add<<<nblk_n, 256, 0, stream>>>(row_start, blk_sums);
  k_scatter2<<<NB * BPB, 256, 0, stream>>>(bucket_buf, bucket_cur, row_start, cursor, sorted_src);

  // layer 1 (MFMA)
  k_gemm1<<<nblk_g1, 256, 0, stream>>>(x, W1f, dinv, h1s);
  k_agg1_gather<<<nblk_nw, 256, 0, stream>>>(h1s, dinv, b1, row_start, cnt, sorted_src, agg1);

  // layer 2 (+ fused log_softmax)
  k_gemm2<<<nblk_g2, 192, 0, stream>>>(agg1, W2p, dinv, h2p);
  k_agg2_gather<<<nblk_nw, 256, 0, stream>>>(h2p, dinv, b2, row_start, cnt, sorted_src, out);
}

// Round 10
// 359.527 us; speedup vs baseline: 1.7465x; 1.0172x over previous
//
#include <hip/hip_runtime.h>
#include <math.h>

#define N_NODES 100000
#define N_EDGES 1600000
#define DIM_IN  256
#define DIM_H   64
#define DIM_C   47
#define DIM_CP  48                            // padded h2 row stride (192B aligned)
#define SCAN_CHUNK 1024                       // elems per scan block (256 thr x 4)
#define NBLK_SCAN ((N_NODES + SCAN_CHUNK - 1) / SCAN_CHUNK)   // 98
#define NB       8                            // dst buckets (one per XCD)
#define BUCKET_W 12500                        // nodes per bucket
#define BCAP     204000                       // per-bucket capacity
#define CHUNK_P1 4096                         // edges per pass-1 block (16/thread)
#define BPB      128                          // pass-2 blocks per bucket

typedef __attribute__((ext_vector_type(8))) short bf16x8;
typedef __attribute__((ext_vector_type(4))) float f32x4;

// RNE float -> bf16 bits
static __device__ __forceinline__ short f2bf(float f) {
  unsigned u = __builtin_bit_cast(unsigned, f);
  u += 0x7FFFu + ((u >> 16) & 1u);
  return (short)(u >> 16);
}

// ---------- zero int buffers ----------
__global__ __launch_bounds__(256) void k_zero(int* __restrict__ cnt,
                                              int* __restrict__ cursor,
                                              int* __restrict__ bucket_cur) {
  int i = blockIdx.x * 256 + threadIdx.x;
  if (i < N_NODES) { cnt[i] = 0; cursor[i] = 0; }
  if (i < NB) bucket_cur[i] = 0;
}

// ---------- pass 1: octant binning + fused per-node degree histogram ----------
__global__ __launch_bounds__(256) void k_bin(const int* __restrict__ src,
                                             const int* __restrict__ dst,
                                             int* __restrict__ cnt,
                                             int* __restrict__ bucket_cur,
                                             unsigned* __restrict__ bucket_buf) {
  __shared__ int lcnt[NB], lbase[NB], lcur[NB];
  if (threadIdx.x < NB) lcnt[threadIdx.x] = 0;
  __syncthreads();
  const int base = blockIdx.x * CHUNK_P1 + threadIdx.x;
  int dreg[16], sreg[16];
#pragma unroll
  for (int it = 0; it < 16; ++it) {
    int e = base + it * 256;
    int d = -1, s = 0;
    if (e < N_EDGES) { d = dst[e]; s = src[e]; }
    dreg[it] = d; sreg[it] = s;
    if (d >= 0) {
      atomicAdd(&lcnt[d / BUCKET_W], 1);
      atomicAdd(&cnt[d], 1);          // degree histogram
    }
  }
  __syncthreads();
  if (threadIdx.x < NB) {
    lbase[threadIdx.x] = atomicAdd(&bucket_cur[threadIdx.x], lcnt[threadIdx.x]);
    lcur[threadIdx.x] = 0;
  }
  __syncthreads();
#pragma unroll
  for (int it = 0; it < 16; ++it) {
    int d = dreg[it];
    if (d >= 0) {
      int b = d / BUCKET_W;
      int r = atomicAdd(&lcur[b], 1);
      unsigned pack = ((unsigned)(d - b * BUCKET_W) << 17) | (unsigned)sreg[it];
      bucket_buf[(size_t)b * BCAP + lbase[b] + r] = pack;
    }
  }
}

// ---------- dinv = rsqrt(deg+1) ----------
__global__ __launch_bounds__(256) void k_dinv(const int* __restrict__ cnt,
                                              float* __restrict__ dinv) {
  int i = blockIdx.x * 256 + threadIdx.x;
  if (i < N_NODES) dinv[i] = rsqrtf((float)cnt[i] + 1.0f);
}

// ---------- pad W2 (64x47) into W2p (64x48) ----------
__global__ __launch_bounds__(256) void k_padW2(const float* __restrict__ W2,
                                               float* __restrict__ W2p) {
  int i = blockIdx.x * 256 + threadIdx.x;
  if (i >= DIM_H * DIM_CP) return;
  int k = i / DIM_CP, j = i % DIM_CP;
  W2p[i] = (j < DIM_C) ? W2[k * DIM_C + j] : 0.f;
}

// ---------- pre-swizzle W1 into per-lane MFMA B-fragment order ----------
__global__ __launch_bounds__(256) void k_prepW1(const float* __restrict__ W1,
                                                short* __restrict__ W1f) {
  int i = blockIdx.x * 256 + threadIdx.x;
  if (i >= 4 * 8 * 64 * 8) return;
  int e    = i & 7;
  int lane = (i >> 3) & 63;
  int ks   = (i >> 9) & 7;
  int wv   = i >> 12;
  int col  = wv * 16 + (lane & 15);
  int k    = ks * 32 + (lane >> 4) * 8 + e;
  W1f[i] = f2bf(W1[k * DIM_H + col]);
}

// ---------- exclusive scan of cnt -> row_start ----------
__global__ __launch_bounds__(256) void k_scan_partial(const int* __restrict__ cnt,
                                                      int* __restrict__ row_start,
                                                      int* __restrict__ blk_sums) {
  __shared__ int ls[256];
  const int tid  = threadIdx.x;
  const int base = blockIdx.x * SCAN_CHUNK + tid * 4;
  int c0 = (base + 0 < N_NODES) ? cnt[base + 0] : 0;
  int c1 = (base + 1 < N_NODES) ? cnt[base + 1] : 0;
  int c2 = (base + 2 < N_NODES) ? cnt[base + 2] : 0;
  int c3 = (base + 3 < N_NODES) ? cnt[base + 3] : 0;
  int tsum = c0 + c1 + c2 + c3;
  ls[tid] = tsum;
  __syncthreads();
  for (int off = 1; off < 256; off <<= 1) {
    int v = (tid >= off) ? ls[tid - off] : 0;
    __syncthreads();
    ls[tid] += v;
    __syncthreads();
  }
  int excl = ls[tid] - tsum;
  if (base + 0 < N_NODES) row_start[base + 0] = excl;
  if (base + 1 < N_NODES) row_start[base + 1] = excl + c0;
  if (base + 2 < N_NODES) row_start[base + 2] = excl + c0 + c1;
  if (base + 3 < N_NODES) row_start[base + 3] = excl + c0 + c1 + c2;
  if (tid == 255) blk_sums[blockIdx.x] = ls[255];
}

__global__ __launch_bounds__(128) void k_scan_blk(int* __restrict__ blk_sums) {
  __shared__ int ls[128];
  const int tid = threadIdx.x;
  int v = (tid < NBLK_SCAN) ? blk_sums[tid] : 0;
  ls[tid] = v;
  __syncthreads();
  for (int off = 1; off < 128; off <<= 1) {
    int u = (tid >= off) ? ls[tid - off] : 0;
    __syncthreads();
    ls[tid] += u;
    __syncthreads();
  }
  if (tid < NBLK_SCAN) blk_sums[tid] = ls[tid] - v;
}

__global__ __launch_bounds__(256) void k_scan_add(int* __restrict__ row_start,
                                                  const int* __restrict__ blk_sums) {
  int i = blockIdx.x * 256 + threadIdx.x;
  if (i < N_NODES) row_start[i] += blk_sums[i / SCAN_CHUNK];
}

// ---------- pass 2: per-bucket fine scatter ----------
__global__ __launch_bounds__(256) void k_scatter2(const unsigned* __restrict__ bucket_buf,
                                                  const int* __restrict__ bucket_cnt,
                                                  const int* __restrict__ row_start,
                                                  int* __restrict__ cursor,
                                                  int* __restrict__ sorted_src) {
  const int b   = blockIdx.x & (NB - 1);
  const int sub = blockIdx.x >> 3;
  const int n_b = bucket_cnt[b];
  const unsigned* buf = bucket_buf + (size_t)b * BCAP;
  for (int i = sub * 256 + (int)threadIdx.x; i < n_b; i += BPB * 256) {
    unsigned pack = buf[i];
    int s = (int)(pack & 0x1FFFFu);
    int d = b * BUCKET_W + (int)(pack >> 17);
    int pos = row_start[d] + atomicAdd(&cursor[d], 1);
    sorted_src[pos] = s;
  }
}

// ---------- layer 1 GEMM on matrix cores: h1s = dinv[n] * (x @ W1) ----------
// All 16 x-loads + 8 B-frag loads issued BEFORE sched_barrier(0) so they are
// all in flight together (R9: compiler sank loads next to each MFMA -> 8
// serial latencies, VGPR=16, 75us). Then cvt+MFMA chain.
__global__ __launch_bounds__(256) void k_gemm1(const float* __restrict__ x,
                                               const short* __restrict__ W1f,
                                               const float* __restrict__ dinv,
                                               float* __restrict__ h1s) {
  const int lane = threadIdx.x & 63;
  const int wv   = threadIdx.x >> 6;
  const int m16  = lane & 15;
  const int kb   = lane >> 4;                 // 0..3
  const int base_row = blockIdx.x * 16;       // 100000 % 16 == 0
  const float* xp = x + (size_t)(base_row + m16) * DIM_IN + kb * 8;
  const bf16x8* wf = (const bf16x8*)W1f + (size_t)wv * 8 * 64 + lane;

  float4 a[16];
  bf16x8 b[8];
#pragma unroll
  for (int ks = 0; ks < 8; ++ks) {
    a[2 * ks]     = *(const float4*)(xp + ks * 32);
    a[2 * ks + 1] = *(const float4*)(xp + ks * 32 + 4);
    b[ks]         = wf[ks * 64];
  }
  __builtin_amdgcn_sched_barrier(0);   // keep all loads issued up front

  f32x4 c = {0.f, 0.f, 0.f, 0.f};
#pragma unroll
  for (int ks = 0; ks < 8; ++ks) {
    float4 a0 = a[2 * ks], a1 = a[2 * ks + 1];
    bf16x8 af;
    af[0] = f2bf(a0.x); af[1] = f2bf(a0.y); af[2] = f2bf(a0.z); af[3] = f2bf(a0.w);
    af[4] = f2bf(a1.x); af[5] = f2bf(a1.y); af[6] = f2bf(a1.z); af[7] = f2bf(a1.w);
    c = __builtin_amdgcn_mfma_f32_16x16x32_bf16(af, b[ks], c, 0, 0, 0);
  }

  const int j0 = wv * 16 + m16;               // output column
#pragma unroll
  for (int r = 0; r < 4; ++r) {
    int row = base_row + kb * 4 + r;
    h1s[(size_t)row * DIM_H + j0] = c[r] * dinv[row];
  }
}

// ---------- agg1 gather: wave per node, lane = channel, 8-way unrolled ----------
__global__ __launch_bounds__(256) void k_agg1_gather(const float* __restrict__ h1s,
                                                     const float* __restrict__ dinv,
                                                     const float* __restrict__ b1,
                                                     const int* __restrict__ row_start,
                                                     const int* __restrict__ cnt,
                                                     const int* __restrict__ sorted_src,
                                                     float* __restrict__ agg1) {
  int n = blockIdx.x * 4 + (threadIdx.x >> 6);
  int j = threadIdx.x & 63;
  if (n >= N_NODES) return;
  int start = row_start[n];
  int deg   = cnt[n];
  float acc0 = h1s[(size_t)n * DIM_H + j];  // self term
  float acc1 = 0.f, acc2 = 0.f, acc3 = 0.f;
  float acc4 = 0.f, acc5 = 0.f, acc6 = 0.f, acc7 = 0.f;
  int k = 0;
  for (; k + 8 <= deg; k += 8) {
    int s0 = sorted_src[start + k + 0];
    int s1 = sorted_src[start + k + 1];
    int s2 = sorted_src[start + k + 2];
    int s3 = sorted_src[start + k + 3];
    int s4 = sorted_src[start + k + 4];
    int s5 = sorted_src[start + k + 5];
    int s6 = sorted_src[start + k + 6];
    int s7 = sorted_src[start + k + 7];
    acc0 += h1s[(size_t)s0 * DIM_H + j];
    acc1 += h1s[(size_t)s1 * DIM_H + j];
    acc2 += h1s[(size_t)s2 * DIM_H + j];
    acc3 += h1s[(size_t)s3 * DIM_H + j];
    acc4 += h1s[(size_t)s4 * DIM_H + j];
    acc5 += h1s[(size_t)s5 * DIM_H + j];
    acc6 += h1s[(size_t)s6 * DIM_H + j];
    acc7 += h1s[(size_t)s7 * DIM_H + j];
  }
  for (; k + 2 <= deg; k += 2) {
    int s0 = sorted_src[start + k + 0];
    int s1 = sorted_src[start + k + 1];
    acc0 += h1s[(size_t)s0 * DIM_H + j];
    acc1 += h1s[(size_t)s1 * DIM_H + j];
  }
  for (; k < deg; ++k)
    acc0 += h1s[(size_t)sorted_src[start + k] * DIM_H + j];
  float di = dinv[n];
  agg1[(size_t)n * DIM_H + j] =
      di * (((acc0 + acc1) + (acc2 + acc3)) + ((acc4 + acc5) + (acc6 + acc7))) + b1[j];
}

// ---------- layer 2 GEMM + ReLU + dinv pre-scale (fp32, batched x-loads) ----------
__global__ __launch_bounds__(192) void k_gemm2(const float* __restrict__ agg1,
                                               const float* __restrict__ W2p,
                                               const float* __restrict__ dinv,
                                               float* __restrict__ h2p) {
  const int lane = threadIdx.x & 63;
  const int j0   = __builtin_amdgcn_readfirstlane((threadIdx.x >> 6) * 16);
  int row = blockIdx.x * 64 + lane;
  if (row >= N_NODES) row = N_NODES - 1;
  const float4* xr = (const float4*)(agg1 + (size_t)row * DIM_H);

  float4 xv[16];
#pragma unroll
  for (int k4 = 0; k4 < 16; ++k4) xv[k4] = xr[k4];
  __builtin_amdgcn_sched_barrier(0);   // all row loads in flight together

  float acc[16];
#pragma unroll
  for (int j = 0; j < 16; ++j) acc[j] = 0.f;

#pragma unroll
  for (int k4 = 0; k4 < DIM_H / 4; ++k4) {
    float4 v = xv[k4];
    v.x = fmaxf(v.x, 0.f); v.y = fmaxf(v.y, 0.f);
    v.z = fmaxf(v.z, 0.f); v.w = fmaxf(v.w, 0.f);
#pragma unroll
    for (int kk = 0; kk < 4; ++kk) {
      float xk = (kk == 0) ? v.x : (kk == 1) ? v.y : (kk == 2) ? v.z : v.w;
      const float* wrow = W2p + (size_t)(4 * k4 + kk) * DIM_CP + j0;  // uniform -> s_load
#pragma unroll
      for (int j = 0; j < 16; ++j)
        acc[j] = fmaf(xk, wrow[j], acc[j]);
    }
  }

  float di = dinv[row];
  float4* out = (float4*)(h2p + (size_t)row * DIM_CP + j0);
#pragma unroll
  for (int j4 = 0; j4 < 4; ++j4)
    out[j4] = make_float4(di * acc[4 * j4], di * acc[4 * j4 + 1],
                          di * acc[4 * j4 + 2], di * acc[4 * j4 + 3]);
}

// ---------- agg2 gather + fused log_softmax: wave per node, 8-way unrolled ----------
__global__ __launch_bounds__(256) void k_agg2_gather(const float* __restrict__ h2p,
                                                     const float* __restrict__ dinv,
                                                     const float* __restrict__ b2,
                                                     const int* __restrict__ row_start,
                                                     const int* __restrict__ cnt,
                                                     const int* __restrict__ sorted_src,
                                                     float* __restrict__ out) {
  int n = blockIdx.x * 4 + (threadIdx.x >> 6);
  int j = threadIdx.x & 63;
  if (n >= N_NODES) return;
  int jj = (j < DIM_C) ? j : DIM_C;  // lanes >=47 read the zero pad
  int start = row_start[n];
  int deg   = cnt[n];
  float acc0 = h2p[(size_t)n * DIM_CP + jj];  // self term
  float acc1 = 0.f, acc2 = 0.f, acc3 = 0.f;
  float acc4 = 0.f, acc5 = 0.f, acc6 = 0.f, acc7 = 0.f;
  int k = 0;
  for (; k + 8 <= deg; k += 8) {
    int s0 = sorted_src[start + k + 0];
    int s1 = sorted_src[start + k + 1];
    int s2 = sorted_src[start + k + 2];
    int s3 = sorted_src[start + k + 3];
    int s4 = sorted_src[start + k + 4];
    int s5 = sorted_src[start + k + 5];
    int s6 = sorted_src[start + k + 6];
    int s7 = sorted_src[start + k + 7];
    acc0 += h2p[(size_t)s0 * DIM_CP + jj];
    acc1 += h2p[(size_t)s1 * DIM_CP + jj];
    acc2 += h2p[(size_t)s2 * DIM_CP + jj];
    acc3 += h2p[(size_t)s3 * DIM_CP + jj];
    acc4 += h2p[(size_t)s4 * DIM_CP + jj];
    acc5 += h2p[(size_t)s5 * DIM_CP + jj];
    acc6 += h2p[(size_t)s6 * DIM_CP + jj];
    acc7 += h2p[(size_t)s7 * DIM_CP + jj];
  }
  for (; k + 2 <= deg; k += 2) {
    int s0 = sorted_src[start + k + 0];
    int s1 = sorted_src[start + k + 1];
    acc0 += h2p[(size_t)s0 * DIM_CP + jj];
    acc1 += h2p[(size_t)s1 * DIM_CP + jj];
  }
  for (; k < deg; ++k)
    acc0 += h2p[(size_t)sorted_src[start + k] * DIM_CP + jj];
  float di = dinv[n];
  float acc = di * (((acc0 + acc1) + (acc2 + acc3)) + ((acc4 + acc5) + (acc6 + acc7)))
            + ((j < DIM_C) ? b2[jj] : 0.f);

  // fused log_softmax over the 47 classes
  float v = (j < DIM_C) ? acc : -INFINITY;
  float m = v;
  for (int o = 32; o; o >>= 1) m = fmaxf(m, __shfl_xor(m, o));
  float ex = (j < DIM_C) ? __expf(v - m) : 0.0f;
  float s = ex;
  for (int o = 32; o; o >>= 1) s += __shfl_xor(s, o);
  if (j < DIM_C) out[(size_t)n * DIM_C + j] = v - m - __logf(s);
}

extern "C" void kernel_launch(void* const* d_in, const int* in_sizes, int n_in,
                              void* d_out, int out_size, void* d_ws, size_t ws_size,
                              hipStream_t stream) {
  const float* x  = (const float*)d_in[0];
  const float* W1 = (const float*)d_in[1];
  const float* b1 = (const float*)d_in[2];
  const float* W2 = (const float*)d_in[3];
  const float* b2 = (const float*)d_in[4];
  const int*   ei = (const int*)d_in[5];
  const int* src = ei;
  const int* dst = ei + N_EDGES;
  float* out = (float*)d_out;

  float* ws   = (float*)d_ws;
  float* dinv = ws;                                   // N
  float* W2p  = dinv + N_NODES;                       // 64*48
  short* W1f  = (short*)(W2p + DIM_H * DIM_CP);       // 16384 shorts
  float* h1s  = (float*)(W1f + 4 * 8 * 64 * 8);       // N*64 (reused for h2p, N*48)
  float* agg1 = h1s + (size_t)N_NODES * DIM_H;        // N*64
  float* h2p  = h1s;                                  // alias: h1s dead after agg1_gather
  int* ibuf        = (int*)(agg1 + (size_t)N_NODES * DIM_H);
  int* cnt         = ibuf;                            // N
  int* cursor      = cnt + N_NODES;                   // N
  int* row_start   = cursor + N_NODES;                // N
  int* blk_sums    = row_start + N_NODES;             // 128
  int* bucket_cur  = blk_sums + 128;                  // 8 (+pad)
  int* sorted_src  = bucket_cur + 64;                 // E
  unsigned* bucket_buf = (unsigned*)(sorted_src + N_EDGES);  // NB*BCAP

  const int nblk_n  = (N_NODES + 255) / 256;
  const int nblk_nw = (N_NODES + 3) / 4;              // wave-per-node gathers
  const int nblk_g1 = N_NODES / 16;                   // 6250 MFMA tiles
  const int nblk_g2 = (N_NODES + 63) / 64;            // fp32 gemm2 tiles
  const int nblk_p1 = (N_EDGES + CHUNK_P1 - 1) / CHUNK_P1;

  // CSR build (two-pass bucket sort) + weight prep
  k_zero<<<nblk_n, 256, 0, stream>>>(cnt, cursor, bucket_cur);
  k_bin<<<nblk_p1, 256, 0, stream>>>(src, dst, cnt, bucket_cur, bucket_buf);
  k_dinv<<<nblk_n, 256, 0, stream>>>(cnt, dinv);
  k_padW2<<<(DIM_H * DIM_CP + 255) / 256, 256, 0, stream>>>(W2, W2p);
  k_prepW1<<<64, 256, 0, stream>>>(W1, W1f);
  k_scan_partial<<<NBLK_SCAN, 256, 0, stream>>>(cnt, row_start, blk_sums);
  k_scan_blk<<<1, 128, 0, stream>>>(blk_sums);
  k_scan_add<<<nblk_n, 256, 0, stream>>>(row_start, blk_sums);
  k_scatter2<<<NB * BPB, 256, 0, stream>>>(bucket_buf, bucket_cur, row_start, cursor, sorted_src);

  // layer 1 (MFMA)
  k_gemm1<<<nblk_g1, 256, 0, stream>>>(x, W1f, dinv, h1s);
  k_agg1_gather<<<nblk_nw, 256, 0, stream>>>(h1s, dinv, b1, row_start, cnt, sorted_src, agg1);

  // layer 2 (+ fused log_softmax)
  k_gemm2<<<nblk_g2, 192, 0, stream>>>(agg1, W2p, dinv, h2p);
  k_agg2_gather<<<nblk_nw, 256, 0, stream>>>(h2p, dinv, b2, row_start, cnt, sorted_src, out);
}